// Round 13
// baseline (106410.095 us; speedup 1.0000x reference)
//
#include <hip/hip_runtime.h>
#include <stdint.h>

#define T_STEPS 4096
#define BATCH 32
#define HID 512
#define BLK_THREADS 1024    // 16 waves = 4/SIMD; unified reg budget 512/lane

// Round 13 = round 12's ZERO-inter-block-sync architecture (one block per
// batch; whole 2048x512 W_hh int8-quantized in ONE CU's register file;
// v_dot4_i32_i8 matvec; LDS+__syncthreads only) with the round-3..11-PROVEN
// storage mechanism: explicit v_accvgpr_write_b32 into AGPRs, read back per
// use with v_accvgpr_read_b32. Round 12's asm("":"+v") pin only forces
// materialization at one point — the allocator spilled all 256 dwords to
// scratch (VGPR_Count=64, FETCH 565 MB, WRITE 300 MB, VALUBusy 1.5%).
// Rounds 3-11: the accvgpr pair held weights on-chip for the full t-loop
// across 8 consecutive rounds (FETCH flat at ~95 MB).
//
// Budget: 256 AGPR + ~60 VGPR < 512 regs/lane at 4 waves/SIMD. Issue math:
// (1024 sdot4 + 1024 aread) x 2cy / SIMD / step ~ 1.7 us + act/barriers
// ~0.3 us => ~8 ms total, deterministic (no cross-CU traffic at all).
//
// Quantization (validated round 12, absmax 0.015625): per-row scale
// rowmax/127 for weights, fixed 127 for h (|h|<1). gate = dot*rowmax/16129.

__device__ inline int sdot4(uint32_t a, uint32_t b, int c) {
#if __has_builtin(__builtin_amdgcn_sdot4)
  return __builtin_amdgcn_sdot4((int)a, (int)b, c, false);
#else
  int d;
  asm("v_dot4_i32_i8 %0, %1, %2, %3" : "=v"(d) : "v"(a), "v"(b), "v"(c));
  return d;
#endif
}

// Explicit AGPR park/fetch — the proven residency mechanism.
__device__ inline uint32_t awrite(uint32_t v) {
  uint32_t a;
  asm("v_accvgpr_write_b32 %0, %1" : "=a"(a) : "v"(v));
  return a;
}
__device__ inline uint32_t aread(uint32_t a) {
  uint32_t v;
  asm("v_accvgpr_read_b32 %0, %1" : "=v"(v) : "a"(a));
  return v;
}

__device__ inline float sigf(float x) { return 1.0f / (1.0f + __expf(-x)); }
__device__ inline float tanh_fast(float x) {
  float a = fabsf(x);
  float e = __expf(-2.0f * a);
  float r = (1.0f - e) / (1.0f + e);
  return copysignf(r, x);
}

__global__ __launch_bounds__(BLK_THREADS)
void lstm_onecu(const float* __restrict__ x0,
                const float* __restrict__ W_ih,
                const float* __restrict__ W_hh,
                const float* __restrict__ b_ih,
                const float* __restrict__ b_hh,
                const float* __restrict__ W_lin,
                const float* __restrict__ b_lin,
                float* __restrict__ y)
{
  __shared__ float x0_lds[T_STEPS];     // 16 KB: this batch's x0 column
  __shared__ float ylds[T_STEPS];       // 16 KB: per-step y partials
  __shared__ float gsum[4 * HID];       // 8 KB: gate sums, indexed by row
  __shared__ uint32_t hq[HID / 4];      // 512 B: h quantized i8, packed x4

  const int tid = threadIdx.x;
  const int b = blockIdx.x;             // batch — blocks fully independent

  // ---- one-time: load + quantize 2 rows of W_hh -> AGPRs ----
  // Lane owns rows r0 = tid (gates i/f) and r1 = tid + 1024 (gates g/o).
  uint32_t wa0[128], wa1[128];          // AGPR handles
  float scl0, scl1;                     // rowmax / (127*127)
  {
    const float4* p0 = (const float4*)(W_hh + (size_t)tid * HID);
    const float4* p1 = (const float4*)(W_hh + (size_t)(tid + 1024) * HID);
    float m0 = 1e-20f, m1 = 1e-20f;
#pragma unroll
    for (int k = 0; k < 128; ++k) {
      float4 a = p0[k];
      m0 = fmaxf(m0, fmaxf(fmaxf(fabsf(a.x), fabsf(a.y)),
                           fmaxf(fabsf(a.z), fabsf(a.w))));
      float4 c = p1[k];
      m1 = fmaxf(m1, fmaxf(fmaxf(fabsf(c.x), fabsf(c.y)),
                           fmaxf(fabsf(c.z), fabsf(c.w))));
    }
    const float i0 = 127.0f / m0, i1 = 127.0f / m1;
    scl0 = m0 / 16129.0f;
    scl1 = m1 / 16129.0f;
#pragma unroll
    for (int k = 0; k < 128; ++k) {
      float4 a = p0[k];
      int q0 = (int)rintf(a.x * i0), q1 = (int)rintf(a.y * i0);
      int q2 = (int)rintf(a.z * i0), q3 = (int)rintf(a.w * i0);
      wa0[k] = awrite((uint32_t)((q0 & 0xff) | ((q1 & 0xff) << 8) |
                                 ((q2 & 0xff) << 16) | ((q3 & 0xff) << 24)));
      float4 c = p1[k];
      int s0 = (int)rintf(c.x * i1), s1 = (int)rintf(c.y * i1);
      int s2 = (int)rintf(c.z * i1), s3 = (int)rintf(c.w * i1);
      wa1[k] = awrite((uint32_t)((s0 & 0xff) | ((s1 & 0xff) << 8) |
                                 ((s2 & 0xff) << 16) | ((s3 & 0xff) << 24)));
    }
  }

  // ---- one-time: x0 column, y partials, h0 = 0 ----
  for (int i = tid; i < T_STEPS; i += BLK_THREADS) {
    x0_lds[i] = x0[i * BATCH + b];
    ylds[i] = 0.f;
  }
  if (tid < HID / 4) hq[tid] = 0u;

  // ---- activation-lane constants (tid < 512: unit u = tid) ----
  float c_state = 0.f;
  float wih_[4] = {0.f, 0.f, 0.f, 0.f}, bs_[4] = {0.f, 0.f, 0.f, 0.f};
  float wlin_u = 0.f;
  if (tid < HID) {
#pragma unroll
    for (int j = 0; j < 4; ++j) {
      int R = j * HID + tid;
      wih_[j] = W_ih[R];
      bs_[j] = b_ih[R] + b_hh[R];
    }
    wlin_u = W_lin[tid];
  }
  const float blin = b_lin[0];

  __syncthreads();

  for (int t = 0; t < T_STEPS; ++t) {
    // ---- matvec: 2 full rows per lane, h broadcast from LDS ----
    int acc0 = 0, acc1 = 0;
    const uint4* hp = (const uint4*)hq;
#pragma unroll
    for (int q = 0; q < 32; ++q) {
      uint4 h4 = hp[q];
      const int k = 4 * q;
      acc0 = sdot4(aread(wa0[k + 0]), h4.x, acc0);
      acc1 = sdot4(aread(wa1[k + 0]), h4.x, acc1);
      acc0 = sdot4(aread(wa0[k + 1]), h4.y, acc0);
      acc1 = sdot4(aread(wa1[k + 1]), h4.y, acc1);
      acc0 = sdot4(aread(wa0[k + 2]), h4.z, acc0);
      acc1 = sdot4(aread(wa1[k + 2]), h4.z, acc1);
      acc0 = sdot4(aread(wa0[k + 3]), h4.w, acc0);
      acc1 = sdot4(aread(wa1[k + 3]), h4.w, acc1);
    }
    gsum[tid]        = (float)acc0 * scl0;   // row r0 (stride-1: no conflicts)
    gsum[tid + 1024] = (float)acc1 * scl1;   // row r1
    __syncthreads();                          // sums ready

    // ---- activation (tid < 512; unit u = tid) ----
    if (tid < HID) {
      const float xv = x0_lds[t];
      float gi = gsum[tid]             + xv * wih_[0] + bs_[0];
      float gf = gsum[tid + HID]       + xv * wih_[1] + bs_[1];
      float gg = gsum[tid + 2 * HID]   + xv * wih_[2] + bs_[2];
      float go = gsum[tid + 3 * HID]   + xv * wih_[3] + bs_[3];
      float si = sigf(gi), sf = sigf(gf), tg = tanh_fast(gg), so = sigf(go);
      c_state = sf * c_state + si * tg;
      float h = so * tanh_fast(c_state);

      // quantize h -> i8 (|h| < 1 strictly => |q| <= 127), pack 4 lanes
      int hb = (int)rintf(h * 127.0f);
      int v1 = __shfl_down(hb, 1, 64);
      int v2 = __shfl_down(hb, 2, 64);
      int v3 = __shfl_down(hb, 3, 64);
      if ((tid & 3) == 0) {
        hq[tid >> 2] = (uint32_t)((hb & 0xff) | ((v1 & 0xff) << 8) |
                                  ((v2 & 0xff) << 16) | ((v3 & 0xff) << 24));
      }

      // y partial: fold 64 units per wave, one LDS atomic per wave
      float p = wlin_u * h;
#pragma unroll
      for (int m = 32; m >= 1; m >>= 1) p += __shfl_xor(p, m, 64);
      if ((tid & 63) == 0) atomicAdd(&ylds[t], p);
    }
    __syncthreads();                          // hq for step t+1 ready
  }

  // ---- drain: sole owner of this batch's y column — plain stores ----
  for (int i = tid; i < T_STEPS; i += BLK_THREADS) {
    y[i * BATCH + b] = ylds[i] + blin + x0_lds[i];
  }
}

extern "C" void kernel_launch(void* const* d_in, const int* in_sizes, int n_in,
                              void* d_out, int out_size, void* d_ws, size_t ws_size,
                              hipStream_t stream) {
  const float* x0    = (const float*)d_in[0];
  const float* W_ih  = (const float*)d_in[1];
  const float* W_hh  = (const float*)d_in[2];
  const float* b_ih  = (const float*)d_in[3];
  const float* b_hh  = (const float*)d_in[4];
  const float* W_lin = (const float*)d_in[5];
  const float* b_lin = (const float*)d_in[6];
  float* y = (float*)d_out;

  // No workspace, no memsets: each block fully owns + overwrites its batch
  // column of y; all state is in-kernel.
  hipLaunchKernelGGL(lstm_onecu, dim3(BATCH), dim3(BLK_THREADS), 0, stream,
                     x0, W_ih, W_hh, b_ih, b_hh, W_lin, b_lin, y);
}

// Round 14
// 16593.849 us; speedup vs baseline: 6.4126x; 6.4126x over previous
//
#include <hip/hip_runtime.h>
#include <stdint.h>

#define T_STEPS 4096
#define BATCH 32
#define HID 512
#define GROUPS 4            // blocks (CUs) per batch
#define BLK_THREADS 1024    // 16 waves
#define NBLOCKS 256         // surplus blocks exit after claim

typedef uint32_t u32x16 __attribute__((ext_vector_type(16)));

// int8 dot4: 4 MACs/instr (proven numerics rounds 12-13: absmax 0.015625).
__device__ inline int sdot4(uint32_t a, uint32_t b, int c) {
#if __has_builtin(__builtin_amdgcn_sdot4)
  return __builtin_amdgcn_sdot4((int)a, (int)b, c, false);
#else
  int d;
  asm("v_dot4_i32_i8 %0, %1, %2, %3" : "=v"(d) : "v"(a), "v"(b), "v"(c));
  return d;
#endif
}

// Explicit AGPR park/fetch — proven resident across the t-loop at the
// 64-AGPR + ~64-VGPR = 128-reg/lane budget (rounds 4-11, FETCH flat).
// Round-13 lesson: the CU register file is 512 KB total (128 regs/lane at
// 16 waves) — 64 weight dwords/lane is the capacity-correct design point.
__device__ inline uint32_t awrite(uint32_t v) {
  uint32_t a;
  asm("v_accvgpr_write_b32 %0, %1" : "=a"(a) : "v"(v));
  return a;
}
__device__ inline uint32_t aread(uint32_t a) {
  uint32_t v;
  asm("v_accvgpr_read_b32 %0, %1" : "=v"(v) : "a"(a));
  return v;
}

__device__ inline uint64_t uni64(const void* p) {
  uint32_t lo = __builtin_amdgcn_readfirstlane((uint32_t)(uintptr_t)p);
  uint32_t hi = __builtin_amdgcn_readfirstlane((uint32_t)((uintptr_t)p >> 32));
  return ((uint64_t)hi << 32) | lo;
}
__device__ inline void kinv() {
  asm volatile("s_dcache_inv" ::: "memory");
}
// 4x s_load_dwordx16 back-to-back, ONE waitcnt = one L2 round trip (r10).
__device__ inline void sload64(uint64_t p, u32x16& h0, u32x16& h1,
                               u32x16& h2, u32x16& h3) {
  asm volatile(
      "s_load_dwordx16 %0, %4, 0x0\n\t"
      "s_load_dwordx16 %1, %4, 0x40\n\t"
      "s_load_dwordx16 %2, %4, 0x80\n\t"
      "s_load_dwordx16 %3, %4, 0xc0\n\t"
      "s_waitcnt lgkmcnt(0)"
      : "=s"(h0), "=s"(h1), "=s"(h2), "=s"(h3)
      : "s"(p) : "memory");
}

__device__ inline float sigf(float x) { return 1.0f / (1.0f + __expf(-x)); }
__device__ inline float tanh_fast(float x) {
  float a = fabsf(x);
  float e = __expf(-2.0f * a);
  float r = (1.0f - e) / (1.0f + e);
  return copysignf(r, x);
}

// Round 14: 4 CUs per batch (capacity-exact), int8 everywhere, distributed
// activation, one barrier/step, round-11 transport.
//   Block = 128 units (512 gate rows x 512 cols). Wave (rg=wv>>2, cs=wv&3):
//   lane l owns rows {gate rg, units u0+l / u0+l+64}, cols 128*cs..+127
//   = 2x32 int8 dwords in AGPRs. h exchange: dword = tag<<16 | i8(u+1)<<8 |
//   i8(u) (2 units/dword, 64 dwords/slice == sload64). Each wave's slice
//   maps 1:1 to producer block cs. Activation: wave wv, lanes 0..7 own
//   units u0+8wv..+7 (c_state per lane), publish 4 tagged dwords, y via
//   one LDS atomic per wave. Weight scales: full-row max via LDS atomicMax
//   reduce (shared across cs slices), gate = int_dot * rowmax/16129.
__global__ __launch_bounds__(BLK_THREADS)
void lstm_i8(const float* __restrict__ x0,
             const float* __restrict__ W_ih,
             const float* __restrict__ W_hh,
             const float* __restrict__ b_ih,
             const float* __restrict__ b_hh,
             const float* __restrict__ W_lin,
             const float* __restrict__ b_lin,
             float* __restrict__ y,
             uint32_t* __restrict__ h_ex,   // [2][BATCH][256] tagged i8-pairs
             int* __restrict__ claim)       // [8][16] per-XCD claim ctrs
{
  __shared__ float x0_lds[T_STEPS];       // 16 KB
  __shared__ float ylds[T_STEPS];         // 16 KB
  __shared__ int   gacc[2][GROUPS][512];  // 16 KB: [parity][cs][block row]
  __shared__ float rmax[512];             // 2 KB: full-row abs-max
  __shared__ int s_bg;

  const int tid = threadIdx.x;

  // ---- claim a (batch, group) slot on THIS block's physical XCD ----
  // 16 slots/XCD = 4 batches x 4 groups; 256 launched blocks guarantee
  // every XCD sees >= 16 arrivals, so the table always fills. Surplus exits.
  if (tid == 0) {
    uint32_t xcc;
    asm volatile("s_getreg_b32 %0, hwreg(HW_REG_XCC_ID)" : "=s"(xcc));
    xcc &= 7;
    int slot = atomicAdd(claim + xcc * 16, 1);
    s_bg = (slot < 16) ? (int)(((4 * xcc + (slot >> 2)) << 2) | (slot & 3))
                       : -1;
  }
  __syncthreads();
  if (s_bg < 0) return;
  const int b  = s_bg >> 2;               // batch (all 4 groups same XCD)
  const int g  = s_bg & 3;                // group
  const int u0 = g * 128;                 // first owned unit
  const int wv = tid >> 6;                // wave 0..15
  const int rg = wv >> 2;                 // gate 0..3 (row-group)
  const int cs = wv & 3;                  // col-slice == producer group
  const int l  = tid & 63;

  // ---- init LDS ----
  for (int i = tid; i < T_STEPS; i += BLK_THREADS) {
    x0_lds[i] = x0[i * BATCH + b];
    ylds[i] = 0.f;
  }
  if (tid < 512) rmax[tid] = 0.f;
  {
    int* gz = &gacc[0][0][0];
    for (int i = tid; i < 2 * GROUPS * 512; i += BLK_THREADS) gz[i] = 0;
  }
  __syncthreads();

  // ---- pass 1: full-row abs-max (LDS atomicMax over the 4 col-slices) ----
  const int r0 = rg * 128 + l;            // block row (gate rg, unit u0+l)
  const int r1 = r0 + 64;                 //               (unit u0+l+64)
  const int R0 = rg * HID + u0 + l;       // global W_hh row
  const int R1 = R0 + 64;
  const float4* p0 = (const float4*)(W_hh + (size_t)R0 * HID + 128 * cs);
  const float4* p1 = (const float4*)(W_hh + (size_t)R1 * HID + 128 * cs);
  {
    float m0 = 1e-20f, m1 = 1e-20f;
#pragma unroll
    for (int k = 0; k < 32; ++k) {
      float4 a = p0[k];
      m0 = fmaxf(m0, fmaxf(fmaxf(fabsf(a.x), fabsf(a.y)),
                           fmaxf(fabsf(a.z), fabsf(a.w))));
      float4 c = p1[k];
      m1 = fmaxf(m1, fmaxf(fmaxf(fabsf(c.x), fabsf(c.y)),
                           fmaxf(fabsf(c.z), fabsf(c.w))));
    }
    atomicMax((int*)&rmax[r0], __float_as_int(m0));  // floats >= 0: int order
    atomicMax((int*)&rmax[r1], __float_as_int(m1));
  }
  __syncthreads();

  // ---- pass 2: quantize to i8, park 64 dwords in AGPRs ----
  uint32_t wa[64];
  {
    const float i0 = 127.0f / rmax[r0];
    const float i1 = 127.0f / rmax[r1];
#pragma unroll
    for (int k = 0; k < 32; ++k) {
      float4 a = p0[k];
      int q0 = (int)rintf(a.x * i0), q1 = (int)rintf(a.y * i0);
      int q2 = (int)rintf(a.z * i0), q3 = (int)rintf(a.w * i0);
      wa[k] = awrite((uint32_t)((q0 & 0xff) | ((q1 & 0xff) << 8) |
                                ((q2 & 0xff) << 16) | ((q3 & 0xff) << 24)));
      float4 c = p1[k];
      int s0 = (int)rintf(c.x * i1), s1 = (int)rintf(c.y * i1);
      int s2 = (int)rintf(c.z * i1), s3 = (int)rintf(c.w * i1);
      wa[32 + k] = awrite((uint32_t)((s0 & 0xff) | ((s1 & 0xff) << 8) |
                                     ((s2 & 0xff) << 16) | ((s3 & 0xff) << 24)));
    }
  }

  // ---- activation-lane constants (lanes 0..7 of every wave) ----
  const int lu = wv * 8 + l;              // unit offset (valid for l < 8)
  const int U  = u0 + lu;                 // global unit
  float c_state = 0.f;
  float wih_[4] = {0.f, 0.f, 0.f, 0.f}, bs_[4] = {0.f, 0.f, 0.f, 0.f};
  float s_[4] = {0.f, 0.f, 0.f, 0.f};
  float wlin_u = 0.f;
  if (l < 8) {
#pragma unroll
    for (int j = 0; j < 4; ++j) {
      int R = j * HID + U;
      wih_[j] = W_ih[R];
      bs_[j] = b_ih[R] + b_hh[R];
      s_[j] = rmax[j * 128 + lu] * (1.0f / 16129.0f);  // rowmax/(127*127)
    }
    wlin_u = W_lin[U];
  }
  const float blin = b_lin[0];

  // ---- exchange addresses ----
  uint32_t* hb = h_ex + (size_t)b * 256;            // parity stride BATCH*256
  const uint64_t dpu[2] = { uni64(hb + 64 * cs),
                            uni64(hb + BATCH * 256 + 64 * cs) };
  uint32_t* pubbase[2] = { hb + g * 64 + wv * 4,
                           hb + BATCH * 256 + g * 64 + wv * 4 };
  __syncthreads();

  int dead = 0;
  for (int t = 0; t < T_STEPS; ++t) {
    const int sl = t & 1, ns = sl ^ 1;

    // ---- poll own 64-dword tagged slice (one L2 round trip per try) ----
    u32x16 h0, h1, h2, h3;
    {
      const uint32_t tw = (uint32_t)t << 16;
      int guard = 0;
      for (;;) {
        kinv();
        sload64(dpu[sl], h0, h1, h2, h3);
        uint32_t bad = 0;
#pragma unroll
        for (int k = 0; k < 16; ++k) {
          bad |= (h0[k] ^ tw) | (h1[k] ^ tw) | (h2[k] ^ tw) | (h3[k] ^ tw);
        }
        if ((bad & 0xffff0000u) == 0u) break;
        if (dead || ++guard > (1 << 20)) { dead = 1; break; }  // anti-hang
        __builtin_amdgcn_s_sleep(1);
      }
    }
    // ---- SALU pack: two i8-pair dwords -> one i8x4 dword ----
    uint32_t pk[32];
#pragma unroll
    for (int e = 0; e < 8; ++e) {
      pk[e]      = (h0[2 * e] & 0xffffu) | (h0[2 * e + 1] << 16);
      pk[8 + e]  = (h1[2 * e] & 0xffffu) | (h1[2 * e + 1] << 16);
      pk[16 + e] = (h2[2 * e] & 0xffffu) | (h2[2 * e + 1] << 16);
      pk[24 + e] = (h3[2 * e] & 0xffffu) | (h3[2 * e + 1] << 16);
    }
    // ---- matvec: 2 rows x 128 cols per lane ----
    int acc0 = 0, acc1 = 0;
#pragma unroll
    for (int k = 0; k < 32; ++k) {
      acc0 = sdot4(aread(wa[k]), pk[k], acc0);
      acc1 = sdot4(aread(wa[32 + k]), pk[k], acc1);
    }
    gacc[sl][cs][r0] = acc0;            // plain stores: (row,cs) unique
    gacc[sl][cs][r1] = acc1;
    __syncthreads();                    // the ONE barrier per step

    // ---- distributed activation: every wave, lanes 0..7 = 8 units ----
    if (l < 8) {
      const float xv = x0_lds[t];
      float gi = (float)(gacc[sl][0][lu] + gacc[sl][1][lu] +
                         gacc[sl][2][lu] + gacc[sl][3][lu]) * s_[0]
                 + xv * wih_[0] + bs_[0];
      float gf = (float)(gacc[sl][0][128 + lu] + gacc[sl][1][128 + lu] +
                         gacc[sl][2][128 + lu] + gacc[sl][3][128 + lu]) * s_[1]
                 + xv * wih_[1] + bs_[1];
      float gg = (float)(gacc[sl][0][256 + lu] + gacc[sl][1][256 + lu] +
                         gacc[sl][2][256 + lu] + gacc[sl][3][256 + lu]) * s_[2]
                 + xv * wih_[2] + bs_[2];
      float go = (float)(gacc[sl][0][384 + lu] + gacc[sl][1][384 + lu] +
                         gacc[sl][2][384 + lu] + gacc[sl][3][384 + lu]) * s_[3]
                 + xv * wih_[3] + bs_[3];
      float si = sigf(gi), sf = sigf(gf), tg = tanh_fast(gg), so = sigf(go);
      c_state = sf * c_state + si * tg;
      float h = so * tanh_fast(c_state);

      // publish: i8 pair + tag, 4 dwords per wave (16B coalesced)
      int q = (int)rintf(h * 127.0f);
      int qn = __shfl_down(q, 1, 64);
      if ((l & 1) == 0) {
        pubbase[ns][l >> 1] = ((uint32_t)(t + 1) << 16) |
                              ((uint32_t)(qn & 0xff) << 8) |
                              (uint32_t)(q & 0xff);
      }
      // y partial: fold 8 units, one LDS atomic per wave
      float p = wlin_u * h;
      p += __shfl_xor(p, 1, 64);
      p += __shfl_xor(p, 2, 64);
      p += __shfl_xor(p, 4, 64);
      if (l == 0) atomicAdd(&ylds[t], p);
    }
  }

  // ---- drain: 4 blocks accumulate into y; g==0 adds bias + residual ----
  __syncthreads();
  for (int i = tid; i < T_STEPS; i += BLK_THREADS) {
    float val = ylds[i];
    if (g == 0) val += blin + x0_lds[i];
    unsafeAtomicAdd(&y[i * BATCH + b], val);
  }
}

extern "C" void kernel_launch(void* const* d_in, const int* in_sizes, int n_in,
                              void* d_out, int out_size, void* d_ws, size_t ws_size,
                              hipStream_t stream) {
  const float* x0    = (const float*)d_in[0];
  const float* W_ih  = (const float*)d_in[1];
  const float* W_hh  = (const float*)d_in[2];
  const float* b_ih  = (const float*)d_in[3];
  const float* b_hh  = (const float*)d_in[4];
  const float* W_lin = (const float*)d_in[5];
  const float* b_lin = (const float*)d_in[6];
  float* y = (float*)d_out;

  uint32_t* h_ex = (uint32_t*)d_ws;                     // [2][32][256] 64 KB
  int* claim = (int*)(h_ex + 2 * BATCH * 256);          // 512 B
  const size_t init_bytes =
      (size_t)2 * BATCH * 256 * sizeof(uint32_t) + 8 * 16 * sizeof(int);

  // memset 0: slot-0 tags = 0 with q = 0 == the h0 = 0 state; claim = 0
  (void)hipMemsetAsync(d_ws, 0, init_bytes, stream);
  (void)hipMemsetAsync(d_out, 0, (size_t)out_size * sizeof(float), stream);

  hipLaunchKernelGGL(lstm_i8, dim3(NBLOCKS), dim3(BLK_THREADS), 0, stream,
                     x0, W_ih, W_hh, b_ih, b_hh, W_lin, b_lin, y, h_ex, claim);
}